// Round 1
// baseline (721.643 us; speedup 1.0000x reference)
//
#include <hip/hip_runtime.h>

// Problem constants
#define D_DIM 256
#define K_CB  1024
#define N_TOT 32768
#define DHW   262144      // D*H*W = 256*1024
#define ZQ_N  8388608     // 32*256*32*32
#define OUT_CODES 8388608
#define OUT_LOSS  8421376 // ZQ_N + N_TOT

// workspace layout (float offsets)
#define WS_ET    0        // 262144 floats: ET[d*1024 + k] (transposed codebook)
#define WS_EN2   262144   // 1024 floats: -0.5*||e_k||^2
#define WS_LOSS  263168   // 1 float accumulator
#define WS_CODES 263680   // 32768 ints

// ---------------------------------------------------------------------------
// prep: transpose embedding (k-major -> d-major), compute -0.5*||e||^2,
// zero the loss accumulator.  grid: 1024 blocks x 64 threads (1 block per k)
// ---------------------------------------------------------------------------
__global__ void vq_prep(const float* __restrict__ emb, float* __restrict__ ws) {
    const int k = blockIdx.x;
    const int t = threadIdx.x;                       // 0..63
    const float4 v = *reinterpret_cast<const float4*>(emb + k * D_DIM + t * 4);
    float s = v.x * v.x + v.y * v.y + v.z * v.z + v.w * v.w;
    float* ET = ws + WS_ET;
    const int d = t * 4;
    ET[(d + 0) * K_CB + k] = v.x;
    ET[(d + 1) * K_CB + k] = v.y;
    ET[(d + 2) * K_CB + k] = v.z;
    ET[(d + 3) * K_CB + k] = v.w;
#pragma unroll
    for (int off = 32; off > 0; off >>= 1) s += __shfl_down(s, off);
    if (t == 0) ws[WS_EN2 + k] = -0.5f * s;
    if (k == 0 && t == 0) ws[WS_LOSS] = 0.0f;
}

// ---------------------------------------------------------------------------
// fused distance-GEMM + argmin.
// grid: 512 blocks x 256 threads.  Block owns 64 rows (one b, contiguous hw).
// Loops over 4 k-tiles of 256 codes; D in 8 chunks of 32 staged in LDS.
// Thread (tx=tid&15, ty=tid>>4) owns rows ty*4..+3, cols {j*64 + tx*4 + c}.
// score = z.e - 0.5||e||^2 ; argmax == argmin of squared distance.
// ---------------------------------------------------------------------------
__global__ __launch_bounds__(256) void vq_argmin(const float* __restrict__ z,
                                                 float* ws,
                                                 float* __restrict__ out) {
    __shared__ float es[32][256];   // 32 KB  e-tile, d-major
    __shared__ float zs[32][64];    // 8 KB   z-tile, d-major
    __shared__ float ens[256];      // 1 KB   -0.5||e||^2 for this k-tile

    const float* ET = ws + WS_ET;
    const int tid = threadIdx.x;
    const int tx = tid & 15;
    const int ty = tid >> 4;
    const int r0 = blockIdx.x * 64;
    const float* zbase = z + (r0 >> 10) * DHW + (r0 & 1023);  // + d*1024 + r

    float bestv[4];
    int   bestk[4];
#pragma unroll
    for (int i = 0; i < 4; ++i) { bestv[i] = -3.0e38f; bestk[i] = 0; }

    const int zd = tid >> 4;          // staging: d row 0..15 (+16)
    const int zr = (tid & 15) * 4;    // staging: row offset within 64

    for (int kt = 0; kt < 4; ++kt) {
        const int k0 = kt * 256;
        float acc[4][16];
#pragma unroll
        for (int i = 0; i < 4; ++i)
#pragma unroll
            for (int j = 0; j < 16; ++j) acc[i][j] = 0.0f;

        for (int dc = 0; dc < 8; ++dc) {
            const int d0 = dc * 32;
            __syncthreads();   // protect LDS reuse from previous chunk
            // stage e-tile: 8 float4 per thread, coalesced from ET
#pragma unroll
            for (int s = 0; s < 8; ++s) {
                const int fidx = tid + s * 256;
                const int dd = fidx >> 6;
                const int c4 = (fidx & 63) * 4;
                *reinterpret_cast<float4*>(&es[dd][c4]) =
                    *reinterpret_cast<const float4*>(&ET[(d0 + dd) * K_CB + k0 + c4]);
            }
            // stage z-tile: 2 float4 per thread, coalesced
#pragma unroll
            for (int s = 0; s < 2; ++s) {
                const int dd = zd + s * 16;
                *reinterpret_cast<float4*>(&zs[dd][zr]) =
                    *reinterpret_cast<const float4*>(&zbase[(d0 + dd) * 1024 + zr]);
            }
            if (dc == 0) ens[tid] = ws[WS_EN2 + k0 + tid];
            __syncthreads();

#pragma unroll 4
            for (int d = 0; d < 32; ++d) {
                const float4 zf = *reinterpret_cast<const float4*>(&zs[d][ty * 4]);
                float4 ev[4];
#pragma unroll
                for (int j = 0; j < 4; ++j)
                    ev[j] = *reinterpret_cast<const float4*>(&es[d][tx * 4 + j * 64]);
                const float za[4] = {zf.x, zf.y, zf.z, zf.w};
#pragma unroll
                for (int i = 0; i < 4; ++i)
#pragma unroll
                    for (int j = 0; j < 4; ++j) {
                        acc[i][j * 4 + 0] += za[i] * ev[j].x;
                        acc[i][j * 4 + 1] += za[i] * ev[j].y;
                        acc[i][j * 4 + 2] += za[i] * ev[j].z;
                        acc[i][j * 4 + 3] += za[i] * ev[j].w;
                    }
            }
        }
        // fold in -0.5||e||^2 and update running argmax (ascending k order)
#pragma unroll
        for (int i = 0; i < 4; ++i)
#pragma unroll
            for (int jc = 0; jc < 16; ++jc) {
                const int col = (jc >> 2) * 64 + tx * 4 + (jc & 3);
                const float sc = acc[i][jc] + ens[col];
                if (sc > bestv[i]) { bestv[i] = sc; bestk[i] = k0 + col; }
            }
    }

    // reduce across the 16 tx lanes sharing each row (consecutive lanes)
#pragma unroll
    for (int i = 0; i < 4; ++i) {
        float bv = bestv[i];
        int   bk = bestk[i];
#pragma unroll
        for (int m = 8; m > 0; m >>= 1) {
            const float ov = __shfl_xor(bv, m);
            const int   ok = __shfl_xor(bk, m);
            if (ov > bv || (ov == bv && ok < bk)) { bv = ov; bk = ok; }
        }
        if (tx == 0) {
            const int gr = r0 + ty * 4 + i;
            reinterpret_cast<int*>(ws + WS_CODES)[gr] = bk;
            out[OUT_CODES + gr] = (float)bk;   // whole d_out is read as f32
        }
    }
}

// ---------------------------------------------------------------------------
// gather z_q = embedding[codes] (back to (B,D,H,W) layout), accumulate loss.
// grid: 8192 blocks x 256 threads, 4 contiguous output elements per thread.
// ---------------------------------------------------------------------------
__global__ __launch_bounds__(256) void vq_gather(const float* __restrict__ z,
                                                 const float* __restrict__ emb,
                                                 float* ws,
                                                 float* __restrict__ out) {
    const int o  = (blockIdx.x * 256 + threadIdx.x) * 4;
    const int b  = o >> 18;
    const int d  = (o >> 10) & 255;
    const int hw = o & 1023;
    const int n  = b * 1024 + hw;
    const int4 c4 = *reinterpret_cast<const int4*>(
        reinterpret_cast<const int*>(ws + WS_CODES) + n);
    const float4 zf = *reinterpret_cast<const float4*>(z + o);
    float4 q;
    q.x = emb[c4.x * D_DIM + d];
    q.y = emb[c4.y * D_DIM + d];
    q.z = emb[c4.z * D_DIM + d];
    q.w = emb[c4.w * D_DIM + d];
    *reinterpret_cast<float4*>(out + o) = q;
    const float dx = q.x - zf.x, dy = q.y - zf.y;
    const float dz = q.z - zf.z, dw = q.w - zf.w;
    float ls = dx * dx + dy * dy + dz * dz + dw * dw;
#pragma unroll
    for (int off = 32; off > 0; off >>= 1) ls += __shfl_down(ls, off);
    if ((threadIdx.x & 63) == 0) atomicAdd(ws + WS_LOSS, ls);
}

__global__ void vq_finalize(const float* __restrict__ ws, float* __restrict__ out) {
    out[OUT_LOSS] = ws[WS_LOSS] * (1.25f / 8388608.0f);
}

// ---------------------------------------------------------------------------
extern "C" void kernel_launch(void* const* d_in, const int* in_sizes, int n_in,
                              void* d_out, int out_size, void* d_ws, size_t ws_size,
                              hipStream_t stream) {
    const float* z   = (const float*)d_in[0];   // (32,256,32,32)
    const float* emb = (const float*)d_in[1];   // (1024,256)
    float* out = (float*)d_out;
    float* ws  = (float*)d_ws;

    vq_prep<<<K_CB, 64, 0, stream>>>(emb, ws);
    vq_argmin<<<N_TOT / 64, 256, 0, stream>>>(z, ws, out);
    vq_gather<<<ZQ_N / 1024, 256, 0, stream>>>(z, emb, ws, out);
    vq_finalize<<<1, 1, 0, stream>>>(ws, out);
}

// Round 2
// 334.522 us; speedup vs baseline: 2.1572x; 2.1572x over previous
//
#include <hip/hip_runtime.h>

// Problem constants
#define D_DIM 256
#define K_CB  1024
#define N_TOT 32768
#define DHW   262144      // D*H*W = 256*1024
#define ZQ_N  8388608     // 32*256*32*32
#define OUT_CODES 8388608
#define OUT_LOSS  8421376 // ZQ_N + N_TOT

// workspace layout (float offsets)
#define WS_ET    0        // 262144 floats: ET[d*1024 + k] (transposed codebook)
#define WS_EN2   262144   // 1024 floats: -0.5*||e_k||^2
#define WS_CODES 263680   // 32768 ints
// loss partials REUSE the ET region (argmin has consumed ET by the time
// vq_gather runs; same-stream ordering makes this safe)
#define WS_PART  0        // 8192 floats: per-block loss partial sums

// ---------------------------------------------------------------------------
// prep: transpose embedding (k-major -> d-major), compute -0.5*||e||^2.
// grid: 1024 blocks x 64 threads (1 block per k)
// ---------------------------------------------------------------------------
__global__ void vq_prep(const float* __restrict__ emb, float* __restrict__ ws) {
    const int k = blockIdx.x;
    const int t = threadIdx.x;                       // 0..63
    const float4 v = *reinterpret_cast<const float4*>(emb + k * D_DIM + t * 4);
    float s = v.x * v.x + v.y * v.y + v.z * v.z + v.w * v.w;
    float* ET = ws + WS_ET;
    const int d = t * 4;
    ET[(d + 0) * K_CB + k] = v.x;
    ET[(d + 1) * K_CB + k] = v.y;
    ET[(d + 2) * K_CB + k] = v.z;
    ET[(d + 3) * K_CB + k] = v.w;
#pragma unroll
    for (int off = 32; off > 0; off >>= 1) s += __shfl_down(s, off);
    if (t == 0) ws[WS_EN2 + k] = -0.5f * s;
}

// ---------------------------------------------------------------------------
// fused distance-GEMM + argmin.
// grid: 512 blocks x 256 threads.  Block owns 64 rows (one b, contiguous hw).
// Loops over 4 k-tiles of 256 codes; D in 8 chunks of 32 staged in LDS.
// Thread (tx=tid&15, ty=tid>>4) owns rows ty*4..+3, cols {j*64 + tx*4 + c}.
// score = z.e - 0.5||e||^2 ; argmax == argmin of squared distance.
// ---------------------------------------------------------------------------
__global__ __launch_bounds__(256) void vq_argmin(const float* __restrict__ z,
                                                 float* ws,
                                                 float* __restrict__ out) {
    __shared__ float es[32][256];   // 32 KB  e-tile, d-major
    __shared__ float zs[32][64];    // 8 KB   z-tile, d-major
    __shared__ float ens[256];      // 1 KB   -0.5||e||^2 for this k-tile

    const float* ET = ws + WS_ET;
    const int tid = threadIdx.x;
    const int tx = tid & 15;
    const int ty = tid >> 4;
    const int r0 = blockIdx.x * 64;
    const float* zbase = z + (r0 >> 10) * DHW + (r0 & 1023);  // + d*1024 + r

    float bestv[4];
    int   bestk[4];
#pragma unroll
    for (int i = 0; i < 4; ++i) { bestv[i] = -3.0e38f; bestk[i] = 0; }

    const int zd = tid >> 4;          // staging: d row 0..15 (+16)
    const int zr = (tid & 15) * 4;    // staging: row offset within 64

    for (int kt = 0; kt < 4; ++kt) {
        const int k0 = kt * 256;
        float acc[4][16];
#pragma unroll
        for (int i = 0; i < 4; ++i)
#pragma unroll
            for (int j = 0; j < 16; ++j) acc[i][j] = 0.0f;

        for (int dc = 0; dc < 8; ++dc) {
            const int d0 = dc * 32;
            __syncthreads();   // protect LDS reuse from previous chunk
            // stage e-tile: 8 float4 per thread, coalesced from ET
#pragma unroll
            for (int s = 0; s < 8; ++s) {
                const int fidx = tid + s * 256;
                const int dd = fidx >> 6;
                const int c4 = (fidx & 63) * 4;
                *reinterpret_cast<float4*>(&es[dd][c4]) =
                    *reinterpret_cast<const float4*>(&ET[(d0 + dd) * K_CB + k0 + c4]);
            }
            // stage z-tile: 2 float4 per thread, coalesced
#pragma unroll
            for (int s = 0; s < 2; ++s) {
                const int dd = zd + s * 16;
                *reinterpret_cast<float4*>(&zs[dd][zr]) =
                    *reinterpret_cast<const float4*>(&zbase[(d0 + dd) * 1024 + zr]);
            }
            if (dc == 0) ens[tid] = ws[WS_EN2 + k0 + tid];
            __syncthreads();

#pragma unroll 4
            for (int d = 0; d < 32; ++d) {
                const float4 zf = *reinterpret_cast<const float4*>(&zs[d][ty * 4]);
                float4 ev[4];
#pragma unroll
                for (int j = 0; j < 4; ++j)
                    ev[j] = *reinterpret_cast<const float4*>(&es[d][tx * 4 + j * 64]);
                const float za[4] = {zf.x, zf.y, zf.z, zf.w};
#pragma unroll
                for (int i = 0; i < 4; ++i)
#pragma unroll
                    for (int j = 0; j < 4; ++j) {
                        acc[i][j * 4 + 0] += za[i] * ev[j].x;
                        acc[i][j * 4 + 1] += za[i] * ev[j].y;
                        acc[i][j * 4 + 2] += za[i] * ev[j].z;
                        acc[i][j * 4 + 3] += za[i] * ev[j].w;
                    }
            }
        }
        // fold in -0.5||e||^2 and update running argmax (ascending k order)
#pragma unroll
        for (int i = 0; i < 4; ++i)
#pragma unroll
            for (int jc = 0; jc < 16; ++jc) {
                const int col = (jc >> 2) * 64 + tx * 4 + (jc & 3);
                const float sc = acc[i][jc] + ens[col];
                if (sc > bestv[i]) { bestv[i] = sc; bestk[i] = k0 + col; }
            }
    }

    // reduce across the 16 tx lanes sharing each row (consecutive lanes)
#pragma unroll
    for (int i = 0; i < 4; ++i) {
        float bv = bestv[i];
        int   bk = bestk[i];
#pragma unroll
        for (int m = 8; m > 0; m >>= 1) {
            const float ov = __shfl_xor(bv, m);
            const int   ok = __shfl_xor(bk, m);
            if (ov > bv || (ov == bv && ok < bk)) { bv = ov; bk = ok; }
        }
        if (tx == 0) {
            const int gr = r0 + ty * 4 + i;
            reinterpret_cast<int*>(ws + WS_CODES)[gr] = bk;
            out[OUT_CODES + gr] = (float)bk;   // whole d_out is read as f32
        }
    }
}

// ---------------------------------------------------------------------------
// gather z_q = embedding[codes] (back to (B,D,H,W) layout), per-block loss
// partial (NO global atomics - they serialized round 1 at 12.8ns each).
// grid: 8192 blocks x 256 threads, 4 contiguous output elements per thread.
// ---------------------------------------------------------------------------
__global__ __launch_bounds__(256) void vq_gather(const float* __restrict__ z,
                                                 const float* __restrict__ emb,
                                                 float* ws,
                                                 float* __restrict__ out) {
    __shared__ float red[4];
    const int o  = (blockIdx.x * 256 + threadIdx.x) * 4;
    const int b  = o >> 18;
    const int d  = (o >> 10) & 255;
    const int hw = o & 1023;
    const int n  = b * 1024 + hw;
    const int4 c4 = *reinterpret_cast<const int4*>(
        reinterpret_cast<const int*>(ws + WS_CODES) + n);
    const float4 zf = *reinterpret_cast<const float4*>(z + o);
    float4 q;
    q.x = emb[c4.x * D_DIM + d];
    q.y = emb[c4.y * D_DIM + d];
    q.z = emb[c4.z * D_DIM + d];
    q.w = emb[c4.w * D_DIM + d];
    *reinterpret_cast<float4*>(out + o) = q;
    const float dx = q.x - zf.x, dy = q.y - zf.y;
    const float dz = q.z - zf.z, dw = q.w - zf.w;
    float ls = dx * dx + dy * dy + dz * dz + dw * dw;
#pragma unroll
    for (int off = 32; off > 0; off >>= 1) ls += __shfl_down(ls, off);
    if ((threadIdx.x & 63) == 0) red[threadIdx.x >> 6] = ls;
    __syncthreads();
    if (threadIdx.x == 0)
        (ws + WS_PART)[blockIdx.x] = red[0] + red[1] + red[2] + red[3];
}

// ---------------------------------------------------------------------------
// finalize: reduce 8192 per-block partials -> loss scalar. 1 block x 256 thr.
// ---------------------------------------------------------------------------
__global__ __launch_bounds__(256) void vq_finalize(const float* __restrict__ ws,
                                                   float* __restrict__ out) {
    __shared__ float red[4];
    const int t = threadIdx.x;
    float s = 0.0f;
#pragma unroll
    for (int i = 0; i < 32; ++i) s += (ws + WS_PART)[t + i * 256];
#pragma unroll
    for (int off = 32; off > 0; off >>= 1) s += __shfl_down(s, off);
    if ((t & 63) == 0) red[t >> 6] = s;
    __syncthreads();
    if (t == 0)
        out[OUT_LOSS] = (red[0] + red[1] + red[2] + red[3]) * (1.25f / 8388608.0f);
}

// ---------------------------------------------------------------------------
extern "C" void kernel_launch(void* const* d_in, const int* in_sizes, int n_in,
                              void* d_out, int out_size, void* d_ws, size_t ws_size,
                              hipStream_t stream) {
    const float* z   = (const float*)d_in[0];   // (32,256,32,32)
    const float* emb = (const float*)d_in[1];   // (1024,256)
    float* out = (float*)d_out;
    float* ws  = (float*)d_ws;

    vq_prep<<<K_CB, 64, 0, stream>>>(emb, ws);
    vq_argmin<<<N_TOT / 64, 256, 0, stream>>>(z, ws, out);
    vq_gather<<<ZQ_N / 1024, 256, 0, stream>>>(z, emb, ws, out);
    vq_finalize<<<1, 1, 0, stream>>>(ws, out);
}

// Round 4
// 270.065 us; speedup vs baseline: 2.6721x; 1.2387x over previous
//
#include <hip/hip_runtime.h>

typedef _Float16 f16;
typedef __attribute__((ext_vector_type(4))) _Float16 f16x4;
typedef __attribute__((ext_vector_type(8))) _Float16 f16x8;
typedef __attribute__((ext_vector_type(4))) float f32x4;

// Problem constants
#define D_DIM 256
#define K_CB  1024
#define N_TOT 32768
#define DHW   262144      // D*H*W per batch = 256*1024
#define ZQ_N  8388608
#define OUT_CODES 8388608
#define OUT_LOSS  8421376

// workspace layout (float offsets)
#define WS_BAUG  0        // 1024*768 f16 = 393216 floats: B_aug[code][768] = [e_hi|e_hi|e_lo]
#define WS_EN2   393216   // 1024 floats: -0.5*||e||^2
#define WS_CODES 394240   // 32768 ints
#define WS_CNT   427008   // 1 int: rescore-list count
#define WS_LIST  427072   // 4096 ints: rows needing exact fp32 rescore
#define WS_PART  431168   // 512 floats: loss partials
#define LIST_CAP 4096
#define EPS_GAP  0.01f    // ~2500x the f16-split score error bound (~4e-6)

// ---------------------------------------------------------------------------
// prep: en2 = -0.5||e||^2 (fp32), build f16-split augmented codebook
// B_aug[code] = [e_hi(256) | e_hi(256) | e_lo(256)]  (pairs with A=[z_hi|z_lo|z_hi])
// grid 1024 x 64
// ---------------------------------------------------------------------------
__global__ void vq_prep(const float* __restrict__ emb, float* __restrict__ ws) {
    const int k = blockIdx.x;
    const int t = threadIdx.x;                       // 0..63
    const float4 v = *reinterpret_cast<const float4*>(emb + k * D_DIM + t * 4);
    float s = v.x * v.x + v.y * v.y + v.z * v.z + v.w * v.w;
#pragma unroll
    for (int off = 32; off > 0; off >>= 1) s += __shfl_down(s, off);
    if (t == 0) ws[WS_EN2 + k] = -0.5f * s;

    const float a[4] = {v.x, v.y, v.z, v.w};
    f16x4 hv, lv;
#pragma unroll
    for (int i = 0; i < 4; ++i) {
        f16 h = (f16)a[i];
        hv[i] = h;
        lv[i] = (f16)(a[i] - (float)h);
    }
    f16* B = reinterpret_cast<f16*>(ws) + k * 768;
    *reinterpret_cast<f16x4*>(B + t * 4)       = hv;
    *reinterpret_cast<f16x4*>(B + 256 + t * 4) = hv;
    *reinterpret_cast<f16x4*>(B + 512 + t * 4) = lv;
    if (k == 0 && t == 0) reinterpret_cast<int*>(ws + WS_CNT)[0] = 0;
}

// ---------------------------------------------------------------------------
// fused f16-split MFMA distance-GEMM + argmax(z.e - 0.5||e||^2) with
// second-best gap tracking.  grid 512 x 256 (4 waves, 2M x 2N).
// Block: 64 rows x 1024 codes, code-tiles of 128, aug-K=768 in chunks of 64.
// Wave tile 32x64: 2 rowfrags x 4 colfrags of 16x16 (mfma_f32_16x16x32_f16).
// LDS As[64][64], Bs[128][64] f16, XOR-swizzled (T2).
// ---------------------------------------------------------------------------
__global__ __launch_bounds__(256) void vq_gemm(const float* __restrict__ z,
                                               float* ws,
                                               float* __restrict__ out) {
    __shared__ __align__(16) f16 As[64 * 64];    // 8 KB  [row][k]
    __shared__ __align__(16) f16 Bs[128 * 64];   // 16 KB [col][k]
    __shared__ float comb[2][64][3];

    const f16* __restrict__ Baug = reinterpret_cast<const f16*>(ws);
    const float* __restrict__ en2 = ws + WS_EN2;
    const int tid = threadIdx.x;
    const int lane = tid & 63;
    const int w = tid >> 6, wm = w >> 1, wn = w & 1;
    const int r0 = blockIdx.x * 64;
    const float* __restrict__ zb = z + (r0 >> 10) * DHW + (r0 & 1023);

    float bv[8], sv[8];
    int   bk[8];
#pragma unroll
    for (int i = 0; i < 8; ++i) { bv[i] = -3.0e38f; sv[i] = -3.0e38f; bk[i] = 0; }

    const int arow = tid & 63;     // A-staging: this thread's row
    const int adg  = tid >> 6;     // A-staging: d-group (= wave id)

    for (int ct = 0; ct < 8; ++ct) {
        const int c0 = ct * 128;
        f32x4 acc[2][4];
#pragma unroll
        for (int i = 0; i < 2; ++i)
#pragma unroll
            for (int j = 0; j < 4; ++j) acc[i][j] = f32x4{0.f, 0.f, 0.f, 0.f};

        for (int ch = 0; ch < 12; ++ch) {
            const int kk0 = ch * 64;
            const int seg = kk0 >> 8;        // 0: z_hi, 1: z_lo, 2: z_hi
            const int d0  = kk0 & 255;
            __syncthreads();
            // ---- stage A: convert 64 rows x 64 d of z to f16 (hi or lo) ----
#pragma unroll
            for (int p = 0; p < 4; ++p) {
                const int dl = adg * 16 + p * 4;
                const int d  = d0 + dl;
                f16x4 vals;
#pragma unroll
                for (int i = 0; i < 4; ++i) {
                    const float x = zb[(d + i) * 1024 + arow];
                    const f16 h = (f16)x;
                    vals[i] = (seg == 1) ? (f16)(x - (float)h) : h;
                }
                const int byte = (arow * 128 + dl * 2) ^ ((arow & 7) << 4);
                *reinterpret_cast<f16x4*>(reinterpret_cast<char*>(As) + byte) = vals;
            }
            // ---- stage B: 128 cols x 64 k from precomputed B_aug ----
#pragma unroll
            for (int p = 0; p < 4; ++p) {
                const int u = tid + p * 256;
                const int col = u >> 3, k8 = (u & 7) * 8;
                const f16x8 vb = *reinterpret_cast<const f16x8*>(
                    Baug + (c0 + col) * 768 + kk0 + k8);
                const int byte = (col * 128 + k8 * 2) ^ ((col & 7) << 4);
                *reinterpret_cast<f16x8*>(reinterpret_cast<char*>(Bs) + byte) = vb;
            }
            __syncthreads();
            // ---- compute: 2 k-steps x (2 rowfrags x 4 colfrags) ----
#pragma unroll
            for (int s = 0; s < 2; ++s) {
                const int klocal = s * 32 + (lane >> 4) * 8;
                f16x8 af[2], bf[4];
#pragma unroll
                for (int i = 0; i < 2; ++i) {
                    const int row = wm * 32 + i * 16 + (lane & 15);
                    const int byte = (row * 128 + klocal * 2) ^ ((row & 7) << 4);
                    af[i] = *reinterpret_cast<const f16x8*>(
                        reinterpret_cast<const char*>(As) + byte);
                }
#pragma unroll
                for (int jf = 0; jf < 4; ++jf) {
                    const int col = wn * 64 + jf * 16 + (lane & 15);
                    const int byte = (col * 128 + klocal * 2) ^ ((col & 7) << 4);
                    bf[jf] = *reinterpret_cast<const f16x8*>(
                        reinterpret_cast<const char*>(Bs) + byte);
                }
#pragma unroll
                for (int i = 0; i < 2; ++i)
#pragma unroll
                    for (int jf = 0; jf < 4; ++jf)
                        acc[i][jf] = __builtin_amdgcn_mfma_f32_16x16x32_f16(
                            af[i], bf[jf], acc[i][jf], 0, 0, 0);
            }
        }
        // ---- epilogue: fold en2, update per-lane running best/second ----
#pragma unroll
        for (int jf = 0; jf < 4; ++jf) {
            const int col = c0 + wn * 64 + jf * 16 + (lane & 15);
            const float e2 = en2[col];
#pragma unroll
            for (int i = 0; i < 2; ++i)
#pragma unroll
                for (int r = 0; r < 4; ++r) {
                    const float v = acc[i][jf][r] + e2;
                    const int idx = i * 4 + r;
                    if (v > bv[idx]) { sv[idx] = bv[idx]; bv[idx] = v; bk[idx] = col; }
                    else if (v > sv[idx]) sv[idx] = v;
                }
        }
    }

    // cross-lane argmax butterfly within 16-lane col groups (rows stay fixed)
#pragma unroll
    for (int m = 1; m <= 8; m <<= 1)
#pragma unroll
        for (int idx = 0; idx < 8; ++idx) {
            const float pv = __shfl_xor(bv[idx], m);
            const float ps = __shfl_xor(sv[idx], m);
            const int   pk = __shfl_xor(bk[idx], m);
            if (pv > bv[idx] || (pv == bv[idx] && pk < bk[idx])) {
                sv[idx] = fmaxf(bv[idx], ps);
                bv[idx] = pv; bk[idx] = pk;
            } else {
                sv[idx] = fmaxf(sv[idx], pv);
            }
        }

    // cross-wave (wn) combine via LDS
    if ((lane & 15) == 0) {
#pragma unroll
        for (int idx = 0; idx < 8; ++idx) {
            const int row = wm * 32 + (idx >> 2) * 16 + (lane >> 4) * 4 + (idx & 3);
            comb[wn][row][0] = bv[idx];
            comb[wn][row][1] = sv[idx];
            comb[wn][row][2] = __int_as_float(bk[idx]);
        }
    }
    __syncthreads();
    if (tid < 64) {
        const int row = tid;
        const float v0 = comb[0][row][0], s0 = comb[0][row][1];
        const int   k0 = __float_as_int(comb[0][row][2]);
        const float v1 = comb[1][row][0], s1 = comb[1][row][1];
        const int   k1 = __float_as_int(comb[1][row][2]);
        float bvf, svf; int bkf;
        if (v1 > v0 || (v1 == v0 && k1 < k0)) { bvf = v1; bkf = k1; svf = fmaxf(v0, s1); }
        else                                  { bvf = v0; bkf = k0; svf = fmaxf(s0, v1); }
        const int n = r0 + row;
        reinterpret_cast<int*>(ws + WS_CODES)[n] = bkf;
        out[OUT_CODES + n] = (float)bkf;
        if (bvf - svf < EPS_GAP) {
            const int pos = atomicAdd(reinterpret_cast<int*>(ws + WS_CNT), 1);
            if (pos < LIST_CAP) reinterpret_cast<int*>(ws + WS_LIST)[pos] = n;
        }
    }
}

// ---------------------------------------------------------------------------
// exact fp32 rescore of near-tie rows (expected ~30). grid 64 x 256.
// ---------------------------------------------------------------------------
__global__ __launch_bounds__(256) void vq_rescore(const float* __restrict__ z,
                                                  const float* __restrict__ emb,
                                                  float* ws,
                                                  float* __restrict__ out) {
    __shared__ float zl[256];
    __shared__ float rv[4];
    __shared__ int   rk[4];
    const int cnt0 = reinterpret_cast<const int*>(ws + WS_CNT)[0];
    const int cnt = cnt0 < LIST_CAP ? cnt0 : LIST_CAP;
    const int t = threadIdx.x;
    for (int it = blockIdx.x; it < cnt; it += gridDim.x) {
        const int n = reinterpret_cast<const int*>(ws + WS_LIST)[it];
        const int b = n >> 10, hw = n & 1023;
        __syncthreads();                       // protect zl reuse across iters
        zl[t] = z[b * DHW + t * 1024 + hw];
        __syncthreads();
        float bvv = -3.0e38f; int bkk = 0;
#pragma unroll
        for (int j = 0; j < 4; ++j) {
            const int k = t + j * 256;
            const float* e = emb + k * D_DIM;
            float dot = 0.f;
#pragma unroll 8
            for (int d = 0; d < 256; d += 4) {
                const float4 ev = *reinterpret_cast<const float4*>(e + d);
                const float4 zv = *reinterpret_cast<const float4*>(zl + d);
                dot += ev.x * zv.x + ev.y * zv.y + ev.z * zv.z + ev.w * zv.w;
            }
            const float v = dot + ws[WS_EN2 + k];
            if (v > bvv || (v == bvv && k < bkk)) { bvv = v; bkk = k; }
        }
#pragma unroll
        for (int m = 1; m <= 32; m <<= 1) {
            const float pv = __shfl_xor(bvv, m);
            const int   pk = __shfl_xor(bkk, m);
            if (pv > bvv || (pv == bvv && pk < bkk)) { bvv = pv; bkk = pk; }
        }
        if ((t & 63) == 0) { rv[t >> 6] = bvv; rk[t >> 6] = bkk; }
        __syncthreads();
        if (t == 0) {
#pragma unroll
            for (int q = 1; q < 4; ++q)
                if (rv[q] > bvv || (rv[q] == bvv && rk[q] < bkk)) { bvv = rv[q]; bkk = rk[q]; }
            reinterpret_cast<int*>(ws + WS_CODES)[n] = bkk;
            out[OUT_CODES + n] = (float)bkk;
        }
    }
}

// ---------------------------------------------------------------------------
// gather z_q = embedding[codes] via LDS-staged embedding rows (coalesced row
// reads). Rows padded to 260 floats = 1040 B so float4 LDS accesses stay
// 16B-aligned (257-pad was 8B-misaligned on odd rows -> ds_*_b128 UB).
// grid 512 x 256: block handles 64 spatial positions x all 256 d.
// ---------------------------------------------------------------------------
__global__ __launch_bounds__(256) void vq_gather(const float* __restrict__ z,
                                                 const float* __restrict__ emb,
                                                 float* ws,
                                                 float* __restrict__ out) {
    __shared__ __align__(16) float el[64][260];   // 64 gathered embedding rows
    __shared__ int   cl[64];
    __shared__ float red[4];
    const int tid = threadIdx.x;
    const int n0 = blockIdx.x * 64;
    const int b = n0 >> 10, hw0 = n0 & 1023;
    if (tid < 64) cl[tid] = reinterpret_cast<const int*>(ws + WS_CODES)[n0 + tid];
    __syncthreads();
#pragma unroll
    for (int p = 0; p < 16; ++p) {
        const int u = tid + p * 256;          // 4096 float4 units
        const int r = u >> 6, f4 = (u & 63) * 4;
        *reinterpret_cast<float4*>(&el[r][f4]) =
            *reinterpret_cast<const float4*>(emb + cl[r] * D_DIM + f4);
    }
    __syncthreads();
    const int hwl = tid & 63, dg = tid >> 6;  // per-wave: dg const, hwl = lane
    const float* zp = z + b * DHW + hw0 + hwl;
    float* op = out + b * DHW + hw0 + hwl;
    float ls = 0.f;
#pragma unroll 4
    for (int dd4 = 0; dd4 < 16; ++dd4) {
        const int d = dg * 64 + dd4 * 4;
        const float4 q = *reinterpret_cast<const float4*>(&el[hwl][d]);
        const float qa[4] = {q.x, q.y, q.z, q.w};
#pragma unroll
        for (int i = 0; i < 4; ++i) {
            const float zv = zp[(d + i) * 1024];
            op[(d + i) * 1024] = qa[i];
            const float df = qa[i] - zv;
            ls += df * df;
        }
    }
#pragma unroll
    for (int m = 32; m > 0; m >>= 1) ls += __shfl_down(ls, m);
    if ((tid & 63) == 0) red[tid >> 6] = ls;
    __syncthreads();
    if (tid == 0) ws[WS_PART + blockIdx.x] = red[0] + red[1] + red[2] + red[3];
}

// ---------------------------------------------------------------------------
// finalize: reduce 512 partials -> loss. 1 block x 256 threads.
// ---------------------------------------------------------------------------
__global__ __launch_bounds__(256) void vq_finalize(const float* __restrict__ ws,
                                                   float* __restrict__ out) {
    __shared__ float red[4];
    const int t = threadIdx.x;
    float s = ws[WS_PART + t] + ws[WS_PART + t + 256];
#pragma unroll
    for (int off = 32; off > 0; off >>= 1) s += __shfl_down(s, off);
    if ((t & 63) == 0) red[t >> 6] = s;
    __syncthreads();
    if (t == 0)
        out[OUT_LOSS] = (red[0] + red[1] + red[2] + red[3]) * (1.25f / 8388608.0f);
}

// ---------------------------------------------------------------------------
extern "C" void kernel_launch(void* const* d_in, const int* in_sizes, int n_in,
                              void* d_out, int out_size, void* d_ws, size_t ws_size,
                              hipStream_t stream) {
    const float* z   = (const float*)d_in[0];   // (32,256,32,32)
    const float* emb = (const float*)d_in[1];   // (1024,256)
    float* out = (float*)d_out;
    float* ws  = (float*)d_ws;

    vq_prep<<<K_CB, 64, 0, stream>>>(emb, ws);
    vq_gemm<<<N_TOT / 64, 256, 0, stream>>>(z, ws, out);
    vq_rescore<<<64, 256, 0, stream>>>(z, emb, ws, out);
    vq_gather<<<ZQ_N / (256 * 64), 256, 0, stream>>>(z, emb, ws, out);
    vq_finalize<<<1, 256, 0, stream>>>(ws, out);
}

// Round 5
// 204.473 us; speedup vs baseline: 3.5293x; 1.3208x over previous
//
#include <hip/hip_runtime.h>

typedef _Float16 f16;
typedef __attribute__((ext_vector_type(4))) _Float16 f16x4;
typedef __attribute__((ext_vector_type(8))) _Float16 f16x8;
typedef __attribute__((ext_vector_type(4))) float f32x4;

// Problem constants
#define D_DIM 256
#define K_CB  1024
#define N_TOT 32768
#define DHW   262144      // D*H*W per batch = 256*1024
#define ZQ_N  8388608
#define OUT_CODES 8388608
#define OUT_LOSS  8421376

// workspace layout (float offsets)
#define WS_BSP   0        // 1024*512 f16 = 262144 floats: Bsplit[code][512]=[e_hi|e_lo]
#define WS_EN2   262144   // 1024 floats: -0.5*||e||^2
#define WS_CODES 263168   // 32768 ints
#define WS_CNT   295936   // 1 int: rescore-list count
#define WS_LIST  296000   // 4096 ints
#define WS_PART  300096   // 512 floats: loss partials
#define LIST_CAP 4096
#define EPS_GAP  0.01f    // ~2500x the f16-split score error bound

// ---------------------------------------------------------------------------
// prep: en2 = -0.5||e||^2 (fp32); Bsplit[code][512] = [e_hi(256) | e_lo(256)]
// grid 1024 x 64
// ---------------------------------------------------------------------------
__global__ void vq_prep(const float* __restrict__ emb, float* __restrict__ ws) {
    const int k = blockIdx.x;
    const int t = threadIdx.x;                       // 0..63
    const float4 v = *reinterpret_cast<const float4*>(emb + k * D_DIM + t * 4);
    float s = v.x * v.x + v.y * v.y + v.z * v.z + v.w * v.w;
#pragma unroll
    for (int off = 32; off > 0; off >>= 1) s += __shfl_down(s, off);
    if (t == 0) ws[WS_EN2 + k] = -0.5f * s;

    const float a[4] = {v.x, v.y, v.z, v.w};
    f16x4 hv, lv;
#pragma unroll
    for (int i = 0; i < 4; ++i) {
        f16 h = (f16)a[i];
        hv[i] = h;
        lv[i] = (f16)(a[i] - (float)h);
    }
    f16* B = reinterpret_cast<f16*>(ws) + k * 512;
    *reinterpret_cast<f16x4*>(B + t * 4)       = hv;
    *reinterpret_cast<f16x4*>(B + 256 + t * 4) = lv;
    if (k == 0 && t == 0) reinterpret_cast<int*>(ws + WS_CNT)[0] = 0;
}

// ---------------------------------------------------------------------------
// fused f16-split MFMA distance-GEMM + argmax with second-best gap tracking.
// grid 512 x 256 (4 waves, 2M x 2N).  Block: 64 rows x 1024 codes.
// A (z as f16 hi+lo) staged to LDS ONCE (round-4 restaged it 8x = 87% of time).
// 64 chunk-iterations: q = ct(8 code-tiles of 128) x 8 {4 e_hi, 4 e_lo} d-chunks.
// e_hi chunks run against BOTH Ahi and Alo (segments 0,1 share B!); e_lo vs Ahi.
// 2-phase pipeline: next B chunk global->regs during compute, ds_write after bar.
// LDS: Ahi 32K + Alo 32K + Bs 16K = 80 KB -> 2 blocks/CU. comb aliases Bs.
// ---------------------------------------------------------------------------
__global__ __launch_bounds__(256, 2) void vq_gemm(const float* __restrict__ z,
                                                  float* ws,
                                                  float* __restrict__ out) {
    __shared__ __align__(16) char lds[81920];
    f16* Ahi = reinterpret_cast<f16*>(lds);            // [64 rows][256 k] swz
    f16* Alo = reinterpret_cast<f16*>(lds + 32768);
    f16* Bs  = reinterpret_cast<f16*>(lds + 65536);    // [128 cols][64 k] swz
    float* comb = reinterpret_cast<float*>(lds + 65536);  // aliases Bs (post-loop)

    const f16* __restrict__ Bsp = reinterpret_cast<const f16*>(ws);
    const float* __restrict__ en2 = ws + WS_EN2;
    const int tid = threadIdx.x;
    const int lane = tid & 63;
    const int w = tid >> 6, wm = w >> 1, wn = w & 1;
    const int r0 = blockIdx.x * 64;
    const float* __restrict__ zb = z + (r0 >> 10) * DHW + (r0 & 1023);

    // ---- stage A once: 64 rows x 256 d -> f16 hi/lo, XOR-swizzled ----
    {
        const int arow = tid & 63;       // lane = row -> coalesced per d
        const int adg  = tid >> 6;       // wave covers 64 d
#pragma unroll
        for (int p = 0; p < 16; ++p) {
            const int d = adg * 64 + p * 4;
            f16x4 hv, lv;
#pragma unroll
            for (int i = 0; i < 4; ++i) {
                const float x = zb[(d + i) * 1024 + arow];
                const f16 h = (f16)x;
                hv[i] = h;
                lv[i] = (f16)(x - (float)h);
            }
            const int byte = (arow * 512 + d * 2) ^ ((arow & 7) << 4);
            *reinterpret_cast<f16x4*>(reinterpret_cast<char*>(Ahi) + byte) = hv;
            *reinterpret_cast<f16x4*>(reinterpret_cast<char*>(Alo) + byte) = lv;
        }
    }

    float bv[8], sv[8];
    int   bk[8];
#pragma unroll
    for (int i = 0; i < 8; ++i) { bv[i] = -3.0e38f; sv[i] = -3.0e38f; bk[i] = 0; }

    f32x4 acc[2][4];
#pragma unroll
    for (int i = 0; i < 2; ++i)
#pragma unroll
        for (int j = 0; j < 4; ++j) acc[i][j] = f32x4{0.f, 0.f, 0.f, 0.f};

    // ---- prologue: load chunk q=0 into regs ----
    f16x8 breg[4], bnext[4];
    float e2v[4];
#pragma unroll
    for (int p = 0; p < 4; ++p) {
        const int u = tid + p * 256;
        breg[p] = *reinterpret_cast<const f16x8*>(
            Bsp + (u >> 3) * 512 + (u & 7) * 8);
    }

    for (int q = 0; q < 64; ++q) {
        __syncthreads();                 // previous chunk's Bs reads done
        // ds_write staged regs (waits vmcnt automatically)
#pragma unroll
        for (int p = 0; p < 4; ++p) {
            const int u = tid + p * 256;
            const int col = u >> 3, k8 = (u & 7) * 8;
            const int byte = (col * 128 + k8 * 2) ^ ((col & 7) << 4);
            *reinterpret_cast<f16x8*>(reinterpret_cast<char*>(Bs) + byte) = breg[p];
        }
        // prefetch next chunk: latency hides under this chunk's MFMA
        if (q < 63) {
            const int qn = q + 1;
            const int c0n = (qn >> 3) << 7;
            const int kbn = (qn & 7) << 6;   // [0..255]=e_hi, [256..511]=e_lo
#pragma unroll
            for (int p = 0; p < 4; ++p) {
                const int u = tid + p * 256;
                bnext[p] = *reinterpret_cast<const f16x8*>(
                    Bsp + (c0n + (u >> 3)) * 512 + kbn + (u & 7) * 8);
            }
        }
        if ((q & 7) == 6) {              // prefetch en2 for this ct's epilogue
            const int c0 = (q >> 3) << 7;
#pragma unroll
            for (int jf = 0; jf < 4; ++jf)
                e2v[jf] = en2[c0 + wn * 64 + jf * 16 + (lane & 15)];
        }
        __syncthreads();                 // Bs visible

        const int kA = (q & 3) << 6;     // A k-offset for this d-chunk
        const bool ehi = ((q >> 2) & 1) == 0;   // e_hi pairs with Ahi AND Alo
#pragma unroll
        for (int s = 0; s < 2; ++s) {
            const int kl = s * 32 + (lane >> 4) * 8;
            f16x8 bf[4];
#pragma unroll
            for (int jf = 0; jf < 4; ++jf) {
                const int cc = wn * 64 + jf * 16 + (lane & 15);
                bf[jf] = *reinterpret_cast<const f16x8*>(
                    reinterpret_cast<const char*>(Bs) +
                    ((cc * 128 + kl * 2) ^ ((cc & 7) << 4)));
            }
            f16x8 ah[2];
#pragma unroll
            for (int i = 0; i < 2; ++i) {
                const int row = wm * 32 + i * 16 + (lane & 15);
                ah[i] = *reinterpret_cast<const f16x8*>(
                    reinterpret_cast<const char*>(Ahi) +
                    ((row * 512 + (kA + kl) * 2) ^ ((row & 7) << 4)));
            }
#pragma unroll
            for (int i = 0; i < 2; ++i)
#pragma unroll
                for (int jf = 0; jf < 4; ++jf)
                    acc[i][jf] = __builtin_amdgcn_mfma_f32_16x16x32_f16(
                        ah[i], bf[jf], acc[i][jf], 0, 0, 0);
            if (ehi) {
                f16x8 al[2];
#pragma unroll
                for (int i = 0; i < 2; ++i) {
                    const int row = wm * 32 + i * 16 + (lane & 15);
                    al[i] = *reinterpret_cast<const f16x8*>(
                        reinterpret_cast<const char*>(Alo) +
                        ((row * 512 + (kA + kl) * 2) ^ ((row & 7) << 4)));
                }
#pragma unroll
                for (int i = 0; i < 2; ++i)
#pragma unroll
                    for (int jf = 0; jf < 4; ++jf)
                        acc[i][jf] = __builtin_amdgcn_mfma_f32_16x16x32_f16(
                            al[i], bf[jf], acc[i][jf], 0, 0, 0);
            }
        }

        if ((q & 7) == 7) {              // epilogue for code-tile ct = q>>3
            const int c0 = (q >> 3) << 7;
#pragma unroll
            for (int jf = 0; jf < 4; ++jf) {
                const int col = c0 + wn * 64 + jf * 16 + (lane & 15);
                const float e2 = e2v[jf];
#pragma unroll
                for (int i = 0; i < 2; ++i)
#pragma unroll
                    for (int r = 0; r < 4; ++r) {
                        const float v = acc[i][jf][r] + e2;
                        const int idx = i * 4 + r;
                        if (v > bv[idx]) { sv[idx] = bv[idx]; bv[idx] = v; bk[idx] = col; }
                        else if (v > sv[idx]) sv[idx] = v;
                    }
            }
#pragma unroll
            for (int i = 0; i < 2; ++i)
#pragma unroll
                for (int j = 0; j < 4; ++j) acc[i][j] = f32x4{0.f, 0.f, 0.f, 0.f};
        }
#pragma unroll
        for (int p = 0; p < 4; ++p) breg[p] = bnext[p];
    }

    // cross-lane argmax butterfly within 16-lane col groups
#pragma unroll
    for (int m = 1; m <= 8; m <<= 1)
#pragma unroll
        for (int idx = 0; idx < 8; ++idx) {
            const float pv = __shfl_xor(bv[idx], m);
            const float ps = __shfl_xor(sv[idx], m);
            const int   pk = __shfl_xor(bk[idx], m);
            if (pv > bv[idx] || (pv == bv[idx] && pk < bk[idx])) {
                sv[idx] = fmaxf(bv[idx], ps);
                bv[idx] = pv; bk[idx] = pk;
            } else {
                sv[idx] = fmaxf(sv[idx], pv);
            }
        }

    __syncthreads();   // all Bs reads done before comb (aliases Bs) is written
    if ((lane & 15) == 0) {
#pragma unroll
        for (int idx = 0; idx < 8; ++idx) {
            const int row = wm * 32 + (idx >> 2) * 16 + (lane >> 4) * 4 + (idx & 3);
            comb[(wn * 64 + row) * 3 + 0] = bv[idx];
            comb[(wn * 64 + row) * 3 + 1] = sv[idx];
            comb[(wn * 64 + row) * 3 + 2] = __int_as_float(bk[idx]);
        }
    }
    __syncthreads();
    if (tid < 64) {
        const int row = tid;
        const float v0 = comb[row * 3 + 0], s0 = comb[row * 3 + 1];
        const int   k0 = __float_as_int(comb[row * 3 + 2]);
        const float v1 = comb[(64 + row) * 3 + 0], s1 = comb[(64 + row) * 3 + 1];
        const int   k1 = __float_as_int(comb[(64 + row) * 3 + 2]);
        float bvf, svf; int bkf;
        if (v1 > v0 || (v1 == v0 && k1 < k0)) { bvf = v1; bkf = k1; svf = fmaxf(v0, s1); }
        else                                  { bvf = v0; bkf = k0; svf = fmaxf(s0, v1); }
        const int n = r0 + row;
        reinterpret_cast<int*>(ws + WS_CODES)[n] = bkf;
        out[OUT_CODES + n] = (float)bkf;
        if (bvf - svf < EPS_GAP) {
            const int pos = atomicAdd(reinterpret_cast<int*>(ws + WS_CNT), 1);
            if (pos < LIST_CAP) reinterpret_cast<int*>(ws + WS_LIST)[pos] = n;
        }
    }
}

// ---------------------------------------------------------------------------
// exact fp32 rescore of near-tie rows (expected ~30). grid 64 x 256.
// ---------------------------------------------------------------------------
__global__ __launch_bounds__(256) void vq_rescore(const float* __restrict__ z,
                                                  const float* __restrict__ emb,
                                                  float* ws,
                                                  float* __restrict__ out) {
    __shared__ float zl[256];
    __shared__ float rv[4];
    __shared__ int   rk[4];
    const int cnt0 = reinterpret_cast<const int*>(ws + WS_CNT)[0];
    const int cnt = cnt0 < LIST_CAP ? cnt0 : LIST_CAP;
    const int t = threadIdx.x;
    for (int it = blockIdx.x; it < cnt; it += gridDim.x) {
        const int n = reinterpret_cast<const int*>(ws + WS_LIST)[it];
        const int b = n >> 10, hw = n & 1023;
        __syncthreads();
        zl[t] = z[b * DHW + t * 1024 + hw];
        __syncthreads();
        float bvv = -3.0e38f; int bkk = 0;
#pragma unroll
        for (int j = 0; j < 4; ++j) {
            const int k = t + j * 256;
            const float* e = emb + k * D_DIM;
            float dot = 0.f;
#pragma unroll 8
            for (int d = 0; d < 256; d += 4) {
                const float4 ev = *reinterpret_cast<const float4*>(e + d);
                const float4 zv = *reinterpret_cast<const float4*>(zl + d);
                dot += ev.x * zv.x + ev.y * zv.y + ev.z * zv.z + ev.w * zv.w;
            }
            const float v = dot + ws[WS_EN2 + k];
            if (v > bvv || (v == bvv && k < bkk)) { bvv = v; bkk = k; }
        }
#pragma unroll
        for (int m = 1; m <= 32; m <<= 1) {
            const float pv = __shfl_xor(bvv, m);
            const int   pk = __shfl_xor(bkk, m);
            if (pv > bvv || (pv == bvv && pk < bkk)) { bvv = pv; bkk = pk; }
        }
        if ((t & 63) == 0) { rv[t >> 6] = bvv; rk[t >> 6] = bkk; }
        __syncthreads();
        if (t == 0) {
#pragma unroll
            for (int q = 1; q < 4; ++q)
                if (rv[q] > bvv || (rv[q] == bvv && rk[q] < bkk)) { bvv = rv[q]; bkk = rk[q]; }
            reinterpret_cast<int*>(ws + WS_CODES)[n] = bkk;
            out[OUT_CODES + n] = (float)bkk;
        }
    }
}

// ---------------------------------------------------------------------------
// gather z_q = embedding[codes] via LDS-staged rows, float4 transpose-write.
// grid 512 x 256: block = 64 spatial positions x 256 d.
// ---------------------------------------------------------------------------
__global__ __launch_bounds__(256) void vq_gather(const float* __restrict__ z,
                                                 const float* __restrict__ emb,
                                                 float* ws,
                                                 float* __restrict__ out) {
    __shared__ __align__(16) float el[64][260];   // rows padded: 1040 B, 16B-aligned
    __shared__ int   cl[64];
    __shared__ float red[4];
    const int tid = threadIdx.x;
    const int n0 = blockIdx.x * 64;
    const int b = n0 >> 10, hw0 = n0 & 1023;
    if (tid < 64) cl[tid] = reinterpret_cast<const int*>(ws + WS_CODES)[n0 + tid];
    __syncthreads();
#pragma unroll
    for (int p = 0; p < 16; ++p) {
        const int u = tid + p * 256;
        const int r = u >> 6, f4 = (u & 63) * 4;
        *reinterpret_cast<float4*>(&el[r][f4]) =
            *reinterpret_cast<const float4*>(emb + cl[r] * D_DIM + f4);
    }
    __syncthreads();
    const int hw4 = (tid & 15) * 4, dg = tid >> 4;   // dg 0..15, 16 d each
    const float* zp = z + b * DHW + hw0 + hw4;
    float* op = out + b * DHW + hw0 + hw4;
    float ls = 0.f;
#pragma unroll
    for (int dd = 0; dd < 16; ++dd) {
        const int d = dg * 16 + dd;
        float4 q;
        q.x = el[hw4 + 0][d]; q.y = el[hw4 + 1][d];
        q.z = el[hw4 + 2][d]; q.w = el[hw4 + 3][d];
        const float4 zv = *reinterpret_cast<const float4*>(zp + d * 1024);
        *reinterpret_cast<float4*>(op + d * 1024) = q;
        const float dx = q.x - zv.x, dy = q.y - zv.y;
        const float dz = q.z - zv.z, dw = q.w - zv.w;
        ls += dx * dx + dy * dy + dz * dz + dw * dw;
    }
#pragma unroll
    for (int m = 32; m > 0; m >>= 1) ls += __shfl_down(ls, m);
    if ((tid & 63) == 0) red[tid >> 6] = ls;
    __syncthreads();
    if (tid == 0) ws[WS_PART + blockIdx.x] = red[0] + red[1] + red[2] + red[3];
}

// ---------------------------------------------------------------------------
// finalize: reduce 512 partials -> loss. 1 block x 256 threads.
// ---------------------------------------------------------------------------
__global__ __launch_bounds__(256) void vq_finalize(const float* __restrict__ ws,
                                                   float* __restrict__ out) {
    __shared__ float red[4];
    const int t = threadIdx.x;
    float s = ws[WS_PART + t] + ws[WS_PART + t + 256];
#pragma unroll
    for (int off = 32; off > 0; off >>= 1) s += __shfl_down(s, off);
    if ((t & 63) == 0) red[t >> 6] = s;
    __syncthreads();
    if (t == 0)
        out[OUT_LOSS] = (red[0] + red[1] + red[2] + red[3]) * (1.25f / 8388608.0f);
}

// ---------------------------------------------------------------------------
extern "C" void kernel_launch(void* const* d_in, const int* in_sizes, int n_in,
                              void* d_out, int out_size, void* d_ws, size_t ws_size,
                              hipStream_t stream) {
    const float* z   = (const float*)d_in[0];   // (32,256,32,32)
    const float* emb = (const float*)d_in[1];   // (1024,256)
    float* out = (float*)d_out;
    float* ws  = (float*)d_ws;

    vq_prep<<<K_CB, 64, 0, stream>>>(emb, ws);
    vq_gemm<<<N_TOT / 64, 256, 0, stream>>>(z, ws, out);
    vq_rescore<<<64, 256, 0, stream>>>(z, emb, ws, out);
    vq_gather<<<ZQ_N / (256 * 64), 256, 0, stream>>>(z, emb, ws, out);
    vq_finalize<<<1, 256, 0, stream>>>(ws, out);
}